// Round 4
// baseline (1379.519 us; speedup 1.0000x reference)
//
#include <hip/hip_runtime.h>
#include <math.h>

namespace {

constexpr int HW    = 56 * 56;       // 3136
constexpr int NB    = 64;
constexpr int CTOT  = 256;
constexpr int CPG   = 16;            // channels per group
constexpr int GRP   = 16;
constexpr int MTOT  = NB * HW;       // 200704 positions per channel
constexpr int NPAIR = 136;           // upper triangle incl. diagonal of 16x16
constexpr int NACC  = CPG + NPAIR;   // 152 accumulators per group
constexpr float EPSR = 1e-4f;
constexpr int NS_IT = 14;            // Newton-Schulz iterations
constexpr int PPW   = NPAIR / 4;     // 34 pairs per wave
constexpr int F2    = HW / 2;        // 1568 float2 chunks per channel per image
constexpr int CTILE = 256;           // cov stage tile: positions per tile
constexpr int NTILE = (HW + CTILE - 1) / CTILE;   // 13 (12 full + 1x64)

__host__ __device__ constexpr int pair_idx(int i, int j) {
    return i * CPG - (i * (i - 1)) / 2 + (j - i);
}

#define GLL16(src, dst)                                                        \
    __builtin_amdgcn_global_load_lds(                                          \
        (const __attribute__((address_space(1))) void*)(src),                  \
        (__attribute__((address_space(3))) void*)(dst), 16, 0, 0)

// Counted waits + raw barrier (no auto vmcnt(0) drain like __syncthreads emits).
// "memory" clobbers keep all LDS/global ops on their side; register-only FMAs may
// drift, which is safe (values already in regs).
#define VMCNT4() asm volatile("s_waitcnt vmcnt(4)" ::: "memory")
#define VMCNT0() asm volatile("s_waitcnt vmcnt(0)" ::: "memory")
#define LGKM0()  asm volatile("s_waitcnt lgkmcnt(0)" ::: "memory")
#define SBAR()   asm volatile("s_barrier" ::: "memory")

// ---------------- Pass 1: channel sums + cross-product sums (one read of x) ----------
// LDS-staged, counted-vmcnt double buffer: per tile each wave issues 4 global_load_lds
// (1 KiB each) for tile t+2, waits vmcnt(4) (tile t landed, t+1 stays IN FLIGHT across
// the barrier), computes tile t, lgkmcnt(0)+barrier releases the buffer. Round-3 used
// __syncthreads, whose vmcnt(0) drained the prefetch every iteration -> serial latency.
// __launch_bounds__(256,4) caps VGPR at 128 (live set ~90) -> 4 blocks/CU.
template<int W>
__device__ __forceinline__ void accum2(const float2 (&v)[CPG],
                                       float (&acc)[PPW], float (&sum)[4]) {
#pragma unroll
    for (int i = 0; i < CPG; ++i) {
#pragma unroll
        for (int j = i; j < CPG; ++j) {
            const int k = pair_idx(i, j);            // unroll-constant
            if (k >= W * PPW && k < (W + 1) * PPW) { // folds at compile time
                acc[k - W * PPW] = fmaf(v[i].x, v[j].x, acc[k - W * PPW]);
                acc[k - W * PPW] = fmaf(v[i].y, v[j].y, acc[k - W * PPW]);
            }
        }
    }
#pragma unroll
    for (int c = 0; c < 4; ++c) sum[c] += v[W * 4 + c].x + v[W * 4 + c].y;
}

template<int W>
__device__ __forceinline__ void writeback(float* __restrict__ dst,
                                          const float (&acc)[PPW],
                                          const float (&sum)[4]) {
#pragma unroll
    for (int k = 0; k < PPW; ++k) atomicAdd(dst + CPG + W * PPW + k, acc[k]);
#pragma unroll
    for (int c = 0; c < 4; ++c) atomicAdd(dst + W * 4 + c, sum[c]);
}

__global__ __launch_bounds__(256, 4)
void cov_kernel(const float* __restrict__ x, float* __restrict__ accg) {
    __shared__ __align__(16) float xs[2][CPG][CTILE];   // 32 KB, double-buffered

    const int bid  = blockIdx.x;          // bid = g*NB + n
    const int g    = bid >> 6;
    const int n    = bid & (NB - 1);
    const int t    = threadIdx.x;
    const int w    = t >> 6;
    const int lane = t & 63;

    const float* xb = x + ((size_t)n * CTOT + (size_t)g * CPG) * HW;

    float acc[PPW], sum[4];
#pragma unroll
    for (int k = 0; k < PPW; ++k) acc[k] = 0.f;
#pragma unroll
    for (int c = 0; c < 4; ++c) sum[c] = 0.f;

    // wave w stages channels 4w..4w+3: lane l writes bytes [16l,16l+16) of row j.
    // Always exactly 4 VMEM insts per wave (tail masks lanes, not instructions),
    // so vmcnt bookkeeping is uniform.
    auto stage = [&](int buf, int tile) {
        const int pos0 = tile * CTILE;
        const int len  = HW - pos0 < CTILE ? HW - pos0 : CTILE;   // 256 or 64
#pragma unroll
        for (int jj = 0; jj < 4; ++jj) {
            const int j = w * 4 + jj;
            if (4 * lane < len)
                GLL16(xb + (size_t)j * HW + pos0 + 4 * lane, &xs[buf][j][0]);
        }
    };

    stage(0, 0);
    stage(1, 1);                          // 8 VMEM in flight per wave

#pragma unroll 1
    for (int tile = 0; tile < NTILE; ++tile) {
        const int cur = tile & 1;
        if (tile < NTILE - 1) VMCNT4();   // tile landed; next tile stays in flight
        else                  VMCNT0();   // last tile: nothing behind it, drain
        SBAR();                           // all waves' rows of this tile visible

        const int pos0 = tile * CTILE;
        const int len  = HW - pos0 < CTILE ? HW - pos0 : CTILE;
#pragma unroll
        for (int h = 0; h < 2; ++h) {
            const int p = h * 128 + 2 * lane;
            if (p < len) {
                float2 v2[CPG];
#pragma unroll
                for (int j = 0; j < CPG; ++j)
                    v2[j] = *(const float2*)&xs[cur][j][p];
                if      (w == 0) accum2<0>(v2, acc, sum);
                else if (w == 1) accum2<1>(v2, acc, sum);
                else if (w == 2) accum2<2>(v2, acc, sum);
                else             accum2<3>(v2, acc, sum);
            }
        }

        LGKM0();                          // all ds_reads of this buffer complete
        SBAR();                           // buffer released; safe to overwrite
        if (tile + 2 < NTILE) stage(cur, tile + 2);
    }

    // wave butterfly: every lane ends with the wave total
#pragma unroll
    for (int k = 0; k < PPW; ++k) {
#pragma unroll
        for (int s = 32; s > 0; s >>= 1) acc[k] += __shfl_xor(acc[k], s, 64);
    }
#pragma unroll
    for (int c = 0; c < 4; ++c) {
#pragma unroll
        for (int s = 32; s > 0; s >>= 1) sum[c] += __shfl_xor(sum[c], s, 64);
    }

    if (lane == 0) {
        float* dst = accg + g * NACC;
        if      (w == 0) writeback<0>(dst, acc, sum);
        else if (w == 1) writeback<1>(dst, acc, sum);
        else if (w == 2) writeback<2>(dst, acc, sum);
        else             writeback<3>(dst, acc, sum);
    }
}

// ---------------- Pass 2: Newton-Schulz inverse sqrt; fold weight/bias/mean in -------
// Outputs (TRANSPOSED for the apply pass): Pout[g][j][i] = w_i * (cov+eps I)^{-1/2}[i][j]
//          bf[g][i] = bias_i - sum_j P[i][j] * mu[j]
__global__ __launch_bounds__(256, 1)
void ns_kernel(const float* __restrict__ accg,
               const float* __restrict__ weight, const float* __restrict__ bias,
               float* __restrict__ Pout, float* __restrict__ bfout) {
    __shared__ float A[CPG][CPG], Y[CPG][CPG], Z[CPG][CPG], T[CPG][CPG];
    __shared__ float mu[CPG];
    __shared__ float s_tr;
    const int g = blockIdx.x;
    const int t = threadIdx.x;
    const int i = t >> 4, j = t & 15;
    const float* a = accg + g * NACC;
    const float invM = 1.0f / (float)MTOT;

    if (t < CPG) mu[t] = a[t] * invM;
    __syncthreads();
    {
        const int lo = i < j ? i : j;
        const int hi = i < j ? j : i;
        float c = a[CPG + pair_idx(lo, hi)] * invM - mu[i] * mu[j];
        if (i == j) c += EPSR;
        A[i][j] = c;
    }
    __syncthreads();
    if (t == 0) {
        float tr = 0.f;
        for (int k = 0; k < CPG; ++k) tr += A[k][k];
        s_tr = tr;
    }
    __syncthreads();
    const float tr = s_tr;
    Y[i][j] = A[i][j] / tr;
    Z[i][j] = (i == j) ? 1.f : 0.f;
    __syncthreads();

    for (int it = 0; it < NS_IT; ++it) {
        float zy = 0.f;
#pragma unroll
        for (int k = 0; k < CPG; ++k) zy += Z[i][k] * Y[k][j];
        const float tij = ((i == j) ? 1.5f : 0.f) - 0.5f * zy;
        T[i][j] = tij;
        __syncthreads();
        float y2 = 0.f, z2 = 0.f;
#pragma unroll
        for (int k = 0; k < CPG; ++k) {
            y2 += Y[i][k] * T[k][j];
            z2 += T[i][k] * Z[k][j];
        }
        __syncthreads();
        Y[i][j] = y2;
        Z[i][j] = z2;
        __syncthreads();
    }

    const float pw = (Z[i][j] / sqrtf(tr)) * weight[g * CPG + i];
    Pout[g * 256 + j * CPG + i] = pw;     // transposed: row j holds column P[.][j]

    T[i][j] = pw;
    __syncthreads();
    if (t < CPG) {
        float o = 0.f;
        for (int k = 0; k < CPG; ++k) o += T[t][k] * mu[k];
        bfout[g * CPG + t] = bias[g * CPG + t] - o;
    }
}

// ---------------- Pass 3: out = Pw . x + bf  (float2 register streaming) -------------
// One block per (n,g) slab; each lane owns float2 position chunks and computes ALL 16
// output channels. Round-3 lesson: `unroll 1` alone doesn't stop the allocator from
// using 256 VGPRs (pipelining) -> spills (FETCH 356 MB vs 205 ideal) at 1 block/CU.
// __launch_bounds__(256, 4) hard-caps at 128 VGPRs; live set ~90 fits without spill;
// 4 blocks/CU = 16 waves/CU, 8 KB of loads in flight per wave.
__global__ __launch_bounds__(256, 4)
void apply_kernel(const float* __restrict__ x, const float* __restrict__ Pg,
                  const float* __restrict__ bfg, float* __restrict__ out) {
    __shared__ __align__(16) float Pl[CPG * CPG];   // Pl[j*16+i] = P[i][j]
    __shared__ float bl[CPG];

    const int slab = blockIdx.x;
    const int g    = slab & (GRP - 1);
    const int n    = slab >> 4;
    const int t    = threadIdx.x;

    Pl[t] = Pg[g * 256 + t];
    if (t < CPG) bl[t] = bfg[g * CPG + t];
    __syncthreads();

    const size_t base = ((size_t)n * CTOT + (size_t)g * CPG) * HW;
    const float* xb = x + base;
    float*       ob = out + base;

#pragma unroll 1
    for (int f2 = t; f2 < F2; f2 += 256) {
        const float* px = xb + 2 * f2;
        float2 xv[CPG];
#pragma unroll
        for (int j = 0; j < CPG; ++j)
            xv[j] = *(const float2*)(px + j * HW);

        float2 acc[CPG];
#pragma unroll
        for (int i = 0; i < CPG; ++i) {
            const float bb = bl[i];
            acc[i] = make_float2(bb, bb);
        }

#pragma unroll
        for (int j = 0; j < CPG; ++j) {
            const float2 xj = xv[j];
            const float4* pc = (const float4*)&Pl[j * CPG];  // column j, wave-uniform
#pragma unroll
            for (int q = 0; q < 4; ++q) {
                const float4 p = pc[q];
                acc[q * 4 + 0].x = fmaf(p.x, xj.x, acc[q * 4 + 0].x);
                acc[q * 4 + 0].y = fmaf(p.x, xj.y, acc[q * 4 + 0].y);
                acc[q * 4 + 1].x = fmaf(p.y, xj.x, acc[q * 4 + 1].x);
                acc[q * 4 + 1].y = fmaf(p.y, xj.y, acc[q * 4 + 1].y);
                acc[q * 4 + 2].x = fmaf(p.z, xj.x, acc[q * 4 + 2].x);
                acc[q * 4 + 2].y = fmaf(p.z, xj.y, acc[q * 4 + 2].y);
                acc[q * 4 + 3].x = fmaf(p.w, xj.x, acc[q * 4 + 3].x);
                acc[q * 4 + 3].y = fmaf(p.w, xj.y, acc[q * 4 + 3].y);
            }
        }

        float* po = ob + 2 * f2;
#pragma unroll
        for (int i = 0; i < CPG; ++i)
            *(float2*)(po + i * HW) = acc[i];
    }
}

} // namespace

extern "C" void kernel_launch(void* const* d_in, const int* in_sizes, int n_in,
                              void* d_out, int out_size, void* d_ws, size_t ws_size,
                              hipStream_t stream) {
    const float* x      = (const float*)d_in[0];
    const float* weight = (const float*)d_in[1];
    const float* bias   = (const float*)d_in[2];
    float* out = (float*)d_out;
    float* ws  = (float*)d_ws;

    float* acc = ws;            // 16 * 152 floats (padded region 2560)
    float* Pw  = ws + 2560;     // 16 * 256 floats
    float* bf  = ws + 6656;     // 16 * 16 floats

    hipMemsetAsync(acc, 0, GRP * NACC * sizeof(float), stream);

    cov_kernel<<<GRP * NB, 256, 0, stream>>>(x, acc);
    ns_kernel<<<GRP, 256, 0, stream>>>(acc, weight, bias, Pw, bf);
    apply_kernel<<<NB * GRP, 256, 0, stream>>>(x, Pw, bf, out);
}

// Round 5
// 1189.079 us; speedup vs baseline: 1.1602x; 1.1602x over previous
//
#include <hip/hip_runtime.h>
#include <math.h>

namespace {

constexpr int HW    = 56 * 56;       // 3136
constexpr int NB    = 64;
constexpr int CTOT  = 256;
constexpr int CPG   = 16;            // channels per group
constexpr int GRP   = 16;
constexpr int MTOT  = NB * HW;       // 200704 positions per channel
constexpr int NPAIR = 136;           // upper triangle incl. diagonal of 16x16
constexpr int NACC  = CPG + NPAIR;   // 152 accumulators per group
constexpr float EPSR = 1e-4f;
constexpr int NS_IT = 14;            // Newton-Schulz iterations
constexpr int PPW   = NPAIR / 4;     // 34 pairs per wave
constexpr int F2    = HW / 2;        // 1568 float2 chunks per channel per image
constexpr int CTILE = 256;           // cov stage tile: positions per tile
constexpr int NTILE = (HW + CTILE - 1) / CTILE;   // 13 (12 full + 1x64)

__host__ __device__ constexpr int pair_idx(int i, int j) {
    return i * CPG - (i * (i - 1)) / 2 + (j - i);
}

#define GLL16(src, dst)                                                        \
    __builtin_amdgcn_global_load_lds(                                          \
        (const __attribute__((address_space(1))) void*)(src),                  \
        (__attribute__((address_space(3))) void*)(dst), 16, 0, 0)

// Counted waits + raw barrier (no auto vmcnt(0) drain like __syncthreads emits).
// "memory" clobbers keep all LDS/global ops on their side; register-only FMAs may
// drift, which is safe (values already in regs).
#define VMCNT4() asm volatile("s_waitcnt vmcnt(4)" ::: "memory")
#define VMCNT0() asm volatile("s_waitcnt vmcnt(0)" ::: "memory")
#define LGKM0()  asm volatile("s_waitcnt lgkmcnt(0)" ::: "memory")
#define SBAR()   asm volatile("s_barrier" ::: "memory")

// ---------------- Pass 1: channel sums + cross-product sums (one read of x) ----------
// LDS-staged, counted-vmcnt double buffer: per tile each wave issues 4 global_load_lds
// (1 KiB each) for tile t+2, waits vmcnt(4) (tile t landed, t+1 stays IN FLIGHT across
// the barrier), computes tile t, lgkmcnt(0)+barrier releases the buffer.
// EMPIRICAL LAW (r2-r4): this hipcc's VGPR cap ~= 256 / launch_bounds_arg2:
// (256)->256 regs, (256,4)->64 regs (r4: ~56 spilled regs -> 1.7 GB FETCH, 3.5x slower).
// (256,2) -> 128-reg cap; live set here ~90 -> no spill, 16 waves/CU.
template<int W>
__device__ __forceinline__ void accum2(const float2 (&v)[CPG],
                                       float (&acc)[PPW], float (&sum)[4]) {
#pragma unroll
    for (int i = 0; i < CPG; ++i) {
#pragma unroll
        for (int j = i; j < CPG; ++j) {
            const int k = pair_idx(i, j);            // unroll-constant
            if (k >= W * PPW && k < (W + 1) * PPW) { // folds at compile time
                acc[k - W * PPW] = fmaf(v[i].x, v[j].x, acc[k - W * PPW]);
                acc[k - W * PPW] = fmaf(v[i].y, v[j].y, acc[k - W * PPW]);
            }
        }
    }
#pragma unroll
    for (int c = 0; c < 4; ++c) sum[c] += v[W * 4 + c].x + v[W * 4 + c].y;
}

template<int W>
__device__ __forceinline__ void writeback(float* __restrict__ dst,
                                          const float (&acc)[PPW],
                                          const float (&sum)[4]) {
#pragma unroll
    for (int k = 0; k < PPW; ++k) atomicAdd(dst + CPG + W * PPW + k, acc[k]);
#pragma unroll
    for (int c = 0; c < 4; ++c) atomicAdd(dst + W * 4 + c, sum[c]);
}

__global__ __launch_bounds__(256, 2)
void cov_kernel(const float* __restrict__ x, float* __restrict__ accg) {
    __shared__ __align__(16) float xs[2][CPG][CTILE];   // 32 KB, double-buffered

    const int bid  = blockIdx.x;          // bid = g*NB + n
    const int g    = bid >> 6;
    const int n    = bid & (NB - 1);
    const int t    = threadIdx.x;
    const int w    = t >> 6;
    const int lane = t & 63;

    const float* xb = x + ((size_t)n * CTOT + (size_t)g * CPG) * HW;

    float acc[PPW], sum[4];
#pragma unroll
    for (int k = 0; k < PPW; ++k) acc[k] = 0.f;
#pragma unroll
    for (int c = 0; c < 4; ++c) sum[c] = 0.f;

    // wave w stages channels 4w..4w+3: lane l writes bytes [16l,16l+16) of row j.
    // Always exactly 4 VMEM insts per wave (tail masks lanes, not instructions),
    // so vmcnt bookkeeping is uniform.
    auto stage = [&](int buf, int tile) {
        const int pos0 = tile * CTILE;
        const int len  = HW - pos0 < CTILE ? HW - pos0 : CTILE;   // 256 or 64
#pragma unroll
        for (int jj = 0; jj < 4; ++jj) {
            const int j = w * 4 + jj;
            if (4 * lane < len)
                GLL16(xb + (size_t)j * HW + pos0 + 4 * lane, &xs[buf][j][0]);
        }
    };

    stage(0, 0);
    stage(1, 1);                          // 8 VMEM in flight per wave

#pragma unroll 1
    for (int tile = 0; tile < NTILE; ++tile) {
        const int cur = tile & 1;
        if (tile < NTILE - 1) VMCNT4();   // tile landed; next tile stays in flight
        else                  VMCNT0();   // last tile: nothing behind it, drain
        SBAR();                           // all waves' rows of this tile visible

        const int pos0 = tile * CTILE;
        const int len  = HW - pos0 < CTILE ? HW - pos0 : CTILE;
#pragma unroll
        for (int h = 0; h < 2; ++h) {
            const int p = h * 128 + 2 * lane;
            if (p < len) {
                float2 v2[CPG];
#pragma unroll
                for (int j = 0; j < CPG; ++j)
                    v2[j] = *(const float2*)&xs[cur][j][p];
                if      (w == 0) accum2<0>(v2, acc, sum);
                else if (w == 1) accum2<1>(v2, acc, sum);
                else if (w == 2) accum2<2>(v2, acc, sum);
                else             accum2<3>(v2, acc, sum);
            }
        }

        LGKM0();                          // all ds_reads of this buffer complete
        SBAR();                           // buffer released; safe to overwrite
        if (tile + 2 < NTILE) stage(cur, tile + 2);
    }

    // wave butterfly: every lane ends with the wave total
#pragma unroll
    for (int k = 0; k < PPW; ++k) {
#pragma unroll
        for (int s = 32; s > 0; s >>= 1) acc[k] += __shfl_xor(acc[k], s, 64);
    }
#pragma unroll
    for (int c = 0; c < 4; ++c) {
#pragma unroll
        for (int s = 32; s > 0; s >>= 1) sum[c] += __shfl_xor(sum[c], s, 64);
    }

    if (lane == 0) {
        float* dst = accg + g * NACC;
        if      (w == 0) writeback<0>(dst, acc, sum);
        else if (w == 1) writeback<1>(dst, acc, sum);
        else if (w == 2) writeback<2>(dst, acc, sum);
        else             writeback<3>(dst, acc, sum);
    }
}

// ---------------- Pass 2: Newton-Schulz inverse sqrt; fold weight/bias/mean in -------
// Outputs (TRANSPOSED for the apply pass): Pout[g][j][i] = w_i * (cov+eps I)^{-1/2}[i][j]
//          bf[g][i] = bias_i - sum_j P[i][j] * mu[j]
__global__ __launch_bounds__(256, 1)
void ns_kernel(const float* __restrict__ accg,
               const float* __restrict__ weight, const float* __restrict__ bias,
               float* __restrict__ Pout, float* __restrict__ bfout) {
    __shared__ float A[CPG][CPG], Y[CPG][CPG], Z[CPG][CPG], T[CPG][CPG];
    __shared__ float mu[CPG];
    __shared__ float s_tr;
    const int g = blockIdx.x;
    const int t = threadIdx.x;
    const int i = t >> 4, j = t & 15;
    const float* a = accg + g * NACC;
    const float invM = 1.0f / (float)MTOT;

    if (t < CPG) mu[t] = a[t] * invM;
    __syncthreads();
    {
        const int lo = i < j ? i : j;
        const int hi = i < j ? j : i;
        float c = a[CPG + pair_idx(lo, hi)] * invM - mu[i] * mu[j];
        if (i == j) c += EPSR;
        A[i][j] = c;
    }
    __syncthreads();
    if (t == 0) {
        float tr = 0.f;
        for (int k = 0; k < CPG; ++k) tr += A[k][k];
        s_tr = tr;
    }
    __syncthreads();
    const float tr = s_tr;
    Y[i][j] = A[i][j] / tr;
    Z[i][j] = (i == j) ? 1.f : 0.f;
    __syncthreads();

    for (int it = 0; it < NS_IT; ++it) {
        float zy = 0.f;
#pragma unroll
        for (int k = 0; k < CPG; ++k) zy += Z[i][k] * Y[k][j];
        const float tij = ((i == j) ? 1.5f : 0.f) - 0.5f * zy;
        T[i][j] = tij;
        __syncthreads();
        float y2 = 0.f, z2 = 0.f;
#pragma unroll
        for (int k = 0; k < CPG; ++k) {
            y2 += Y[i][k] * T[k][j];
            z2 += T[i][k] * Z[k][j];
        }
        __syncthreads();
        Y[i][j] = y2;
        Z[i][j] = z2;
        __syncthreads();
    }

    const float pw = (Z[i][j] / sqrtf(tr)) * weight[g * CPG + i];
    Pout[g * 256 + j * CPG + i] = pw;     // transposed: row j holds column P[.][j]

    T[i][j] = pw;
    __syncthreads();
    if (t < CPG) {
        float o = 0.f;
        for (int k = 0; k < CPG; ++k) o += T[t][k] * mu[k];
        bfout[g * CPG + t] = bias[g * CPG + t] - o;
    }
}

// ---------------- Pass 3: out = Pw . x + bf  (float2 register streaming) -------------
// One block per (n,g) slab; each lane owns float2 position chunks and computes ALL 16
// output channels. Live set: xv(32) + acc(32) + addressing ~= 80 regs.
// (256,2) -> 128-reg cap (see empirical law above): fits with headroom, no spill,
// 4 waves/SIMD = 16 waves/CU, grid 1024 = exactly 4 blocks/CU.
__global__ __launch_bounds__(256, 2)
void apply_kernel(const float* __restrict__ x, const float* __restrict__ Pg,
                  const float* __restrict__ bfg, float* __restrict__ out) {
    __shared__ __align__(16) float Pl[CPG * CPG];   // Pl[j*16+i] = P[i][j]
    __shared__ float bl[CPG];

    const int slab = blockIdx.x;
    const int g    = slab & (GRP - 1);
    const int n    = slab >> 4;
    const int t    = threadIdx.x;

    Pl[t] = Pg[g * 256 + t];
    if (t < CPG) bl[t] = bfg[g * CPG + t];
    __syncthreads();

    const size_t base = ((size_t)n * CTOT + (size_t)g * CPG) * HW;
    const float* xb = x + base;
    float*       ob = out + base;

#pragma unroll 1
    for (int f2 = t; f2 < F2; f2 += 256) {
        const float* px = xb + 2 * f2;
        float2 xv[CPG];
#pragma unroll
        for (int j = 0; j < CPG; ++j)
            xv[j] = *(const float2*)(px + j * HW);

        float2 acc[CPG];
#pragma unroll
        for (int i = 0; i < CPG; ++i) {
            const float bb = bl[i];
            acc[i] = make_float2(bb, bb);
        }

#pragma unroll
        for (int j = 0; j < CPG; ++j) {
            const float2 xj = xv[j];
            const float4* pc = (const float4*)&Pl[j * CPG];  // column j, wave-uniform
#pragma unroll
            for (int q = 0; q < 4; ++q) {
                const float4 p = pc[q];
                acc[q * 4 + 0].x = fmaf(p.x, xj.x, acc[q * 4 + 0].x);
                acc[q * 4 + 0].y = fmaf(p.x, xj.y, acc[q * 4 + 0].y);
                acc[q * 4 + 1].x = fmaf(p.y, xj.x, acc[q * 4 + 1].x);
                acc[q * 4 + 1].y = fmaf(p.y, xj.y, acc[q * 4 + 1].y);
                acc[q * 4 + 2].x = fmaf(p.z, xj.x, acc[q * 4 + 2].x);
                acc[q * 4 + 2].y = fmaf(p.z, xj.y, acc[q * 4 + 2].y);
                acc[q * 4 + 3].x = fmaf(p.w, xj.x, acc[q * 4 + 3].x);
                acc[q * 4 + 3].y = fmaf(p.w, xj.y, acc[q * 4 + 3].y);
            }
        }

        float* po = ob + 2 * f2;
#pragma unroll
        for (int i = 0; i < CPG; ++i)
            *(float2*)(po + i * HW) = acc[i];
    }
}

} // namespace

extern "C" void kernel_launch(void* const* d_in, const int* in_sizes, int n_in,
                              void* d_out, int out_size, void* d_ws, size_t ws_size,
                              hipStream_t stream) {
    const float* x      = (const float*)d_in[0];
    const float* weight = (const float*)d_in[1];
    const float* bias   = (const float*)d_in[2];
    float* out = (float*)d_out;
    float* ws  = (float*)d_ws;

    float* acc = ws;            // 16 * 152 floats (padded region 2560)
    float* Pw  = ws + 2560;     // 16 * 256 floats
    float* bf  = ws + 6656;     // 16 * 16 floats

    hipMemsetAsync(acc, 0, GRP * NACC * sizeof(float), stream);

    cov_kernel<<<GRP * NB, 256, 0, stream>>>(x, acc);
    ns_kernel<<<GRP, 256, 0, stream>>>(acc, weight, bias, Pw, bf);
    apply_kernel<<<NB * GRP, 256, 0, stream>>>(x, Pw, bf, out);
}